// Round 2
// baseline (325.050 us; speedup 1.0000x reference)
//
#include <hip/hip_runtime.h>
#include <math.h>
#include <stdint.h>

// Problem constants (B=16, I=256, T=8192), x float32, out float32
#define T_LEN 8192
#define NSTEP 8189   // T-3 sampled steps
#define NB 16
#define NI 256
#define OUTT 8190    // T-2 output time length
#define CHUNK 128
#define NCHUNK 64    // 64*128 = 8192 >= NSTEP

// ---------------- threefry2x32 (JAX-compatible, 20 rounds) ----------------
__device__ __forceinline__ uint32_t rotl32(uint32_t v, int r) {
  return (v << r) | (v >> (32 - r));
}

__device__ __forceinline__ void tf2x32(uint32_t k0, uint32_t k1,
                                       uint32_t x0, uint32_t x1,
                                       uint32_t& o0, uint32_t& o1) {
  uint32_t k2 = k0 ^ k1 ^ 0x1BD11BDAu;
  x0 += k0; x1 += k1;
  // group 1 (rot set A: 13,15,26,6)
  x0 += x1; x1 = rotl32(x1, 13); x1 ^= x0;
  x0 += x1; x1 = rotl32(x1, 15); x1 ^= x0;
  x0 += x1; x1 = rotl32(x1, 26); x1 ^= x0;
  x0 += x1; x1 = rotl32(x1,  6); x1 ^= x0;
  x0 += k1; x1 += k2 + 1u;
  // group 2 (rot set B: 17,29,16,24)
  x0 += x1; x1 = rotl32(x1, 17); x1 ^= x0;
  x0 += x1; x1 = rotl32(x1, 29); x1 ^= x0;
  x0 += x1; x1 = rotl32(x1, 16); x1 ^= x0;
  x0 += x1; x1 = rotl32(x1, 24); x1 ^= x0;
  x0 += k2; x1 += k0 + 2u;
  // group 3 (A)
  x0 += x1; x1 = rotl32(x1, 13); x1 ^= x0;
  x0 += x1; x1 = rotl32(x1, 15); x1 ^= x0;
  x0 += x1; x1 = rotl32(x1, 26); x1 ^= x0;
  x0 += x1; x1 = rotl32(x1,  6); x1 ^= x0;
  x0 += k0; x1 += k1 + 3u;
  // group 4 (B)
  x0 += x1; x1 = rotl32(x1, 17); x1 ^= x0;
  x0 += x1; x1 = rotl32(x1, 29); x1 ^= x0;
  x0 += x1; x1 = rotl32(x1, 16); x1 ^= x0;
  x0 += x1; x1 = rotl32(x1, 24); x1 ^= x0;
  x0 += k1; x1 += k2 + 4u;
  // group 5 (A)
  x0 += x1; x1 = rotl32(x1, 13); x1 ^= x0;
  x0 += x1; x1 = rotl32(x1, 15); x1 ^= x0;
  x0 += x1; x1 = rotl32(x1, 26); x1 ^= x0;
  x0 += x1; x1 = rotl32(x1,  6); x1 ^= x0;
  x0 += k2; x1 += k0 + 5u;
  o0 = x0; o1 = x1;
}

// Correctly-rounded float32 log via double precision
__device__ __forceinline__ float f32log_cr(float x) {
  return (float)log((double)x);
}

// Replicates jax uniform(minval=tiny,maxval=1) -> gumbel, exact f32 semantics:
// u' = f*(1-tiny)+tiny = f + tiny; rounds to f unless f==0 (-> tiny).
__device__ __forceinline__ float bits_to_gumbel(uint32_t bits) {
  uint32_t fb = (bits >> 9) | 0x3F800000u;
  float u = __uint_as_float(fb) - 1.0f;           // exact, in [0, 1)
  if (u == 0.0f) u = 1.17549435e-38f;             // finfo(f32).tiny
  float inner = f32log_cr(u);                     // < 0
  float outer = f32log_cr(-inner);
  return -outer;
}

// -------- Kernel 1: per-(step t, batch b) decision byte (a_n | a_s<<2) -----
// Partitionable threefry: keys[t] = tf(key,(0,t)); bits[q] = o0^o1 of tf(keys[t],(0,q))
__global__ void k_dec(const int* __restrict__ seedp, uint8_t* __restrict__ dec) {
  int t = blockIdx.x * blockDim.x + threadIdx.x;
  int b = blockIdx.y;
  if (t >= NSTEP) return;

  uint32_t sk0 = 0u;                      // threefry_seed(int32 seed): hi word = 0
  uint32_t sk1 = (uint32_t)seedp[0];

  uint32_t kt0, kt1;
  tf2x32(sk0, sk1, 0u, (uint32_t)t, kt0, kt1);    // split key for step t

  float g[3];
#pragma unroll
  for (int e = 0; e < 3; ++e) {
    uint32_t o0, o1;
    tf2x32(kt0, kt1, 0u, (uint32_t)(3 * b + e), o0, o1);
    g[e] = bits_to_gumbel(o0 ^ o1);
  }

  // logits: mirror numpy double arithmetic then f32 cast, then f32 log
  const double pd = 0.1;
  const double sd = 1.0 - 2.0 * 0.1;      // bit-identical to python double
  const float Lp  = f32log_cr((float)pd);
  const float Ls  = f32log_cr((float)sd);
  const float Lb1 = f32log_cr((float)(sd / (pd + sd)));  // special row k=1
  const float Lb2 = f32log_cr((float)(pd / (pd + sd)));  // special row k=2

  // normal row argmax (first-max tie-break, matches jnp.argmax)
  float z0 = g[0] + Lp, z1 = g[1] + Ls, z2 = g[2] + Lp;
  int an = 0; float best = z0;
  if (z1 > best) { best = z1; an = 1; }
  if (z2 > best) { an = 2; }
  // special row: k=0 is log(0) = -inf, never wins; tie -> index 1
  int as_ = ((g[2] + Lb2) > (g[1] + Lb1)) ? 2 : 1;

  dec[b * T_LEN + t] = (uint8_t)(an | (as_ << 2));
}

// -------- Chain as 9-state automaton: sigma = prev2*3 + prev1 --------------
__device__ __forceinline__ int chain_step(int sigma, uint32_t dv) {
  int s = (sigma == 5) ? (int)(dv >> 2) : (int)(dv & 3u);
  return (sigma % 3) * 3 + s;
}

// Phase A: speculative chunk maps — end state for each of 9 entry states
__global__ void k_spec(const uint8_t* __restrict__ dec, uint8_t* __restrict__ Mend) {
  int c = blockIdx.x, b = blockIdx.y;
  int s0 = threadIdx.x;
  if (s0 >= 9) return;
  int sigma = s0;
  int t0 = c * CHUNK;
  int t1 = min(t0 + CHUNK, NSTEP);
  const uint8_t* d = dec + b * T_LEN;
  for (int t = t0; t < t1; ++t) sigma = chain_step(sigma, d[t]);
  Mend[(c * NB + b) * 9 + s0] = (uint8_t)sigma;
}

// Phase B: sequential fold over chunk maps, record entry states
__global__ void k_fold(const uint8_t* __restrict__ Mend, uint8_t* __restrict__ entry) {
  __shared__ uint8_t m[NCHUNK * NB * 9];
  for (int i = threadIdx.x; i < NCHUNK * NB * 9; i += blockDim.x) m[i] = Mend[i];
  __syncthreads();
  int b = threadIdx.x;
  if (b < NB) {
    int sigma = 4;  // (prev2,prev1) = (1,1)
    for (int c = 0; c < NCHUNK; ++c) {
      entry[c * NB + b] = (uint8_t)sigma;
      sigma = m[(c * NB + b) * 9 + sigma];
    }
  }
}

// Phase C: re-walk each chunk with known entry state, emit shifted states
// st2[b][j] = st[b][j+1]
__global__ void k_apply(const uint8_t* __restrict__ dec, const uint8_t* __restrict__ entry,
                        uint8_t* __restrict__ st2) {
  int b = blockIdx.x;
  int c = threadIdx.x;
  if (c >= NCHUNK) return;
  int sigma = entry[c * NB + b];
  const uint8_t* d = dec + b * T_LEN;
  uint8_t* s2 = st2 + b * T_LEN;
  if (c == 0) s2[0] = 1;  // st[1] = 1
  int t0 = c * CHUNK, t1 = min(t0 + CHUNK, NSTEP);
  for (int t = t0; t < t1; ++t) {
    uint32_t dv = d[t];
    int s = (sigma == 5) ? (int)(dv >> 2) : (int)(dv & 3u);
    s2[t + 1] = (uint8_t)s;   // st[t+2] -> st2[t+1]
    sigma = (sigma % 3) * 3 + s;
  }
}

// -------- Gather (f32): out[b,i,j] = x[b,i, j + st2[b][j]] -----------------
__global__ void k_gather(const float* __restrict__ x, const uint8_t* __restrict__ st2,
                         float* __restrict__ out) {
  int j = blockIdx.x * blockDim.x + threadIdx.x;
  int i = blockIdx.y;
  int b = blockIdx.z;
  if (j >= OUTT) return;
  int s = st2[b * T_LEN + j];
  size_t row = (size_t)(b * NI + i);
  out[row * OUTT + j] = x[row * T_LEN + j + s];
}

extern "C" void kernel_launch(void* const* d_in, const int* in_sizes, int n_in,
                              void* d_out, int out_size, void* d_ws, size_t ws_size,
                              hipStream_t stream) {
  const float* x   = (const float*)d_in[0];   // float32 input
  const int* seedp = (const int*)d_in[1];
  float* out       = (float*)d_out;           // float32 output

  uint8_t* ws    = (uint8_t*)d_ws;
  uint8_t* dec   = ws;                        // 16*8192 = 131072 B
  uint8_t* st2   = dec + NB * T_LEN;          // 131072 B
  uint8_t* Mend  = st2 + NB * T_LEN;          // 64*16*9 = 9216 B
  uint8_t* entry = Mend + NCHUNK * NB * 9;    // 64*16 = 1024 B

  k_dec<<<dim3((NSTEP + 255) / 256, NB), 256, 0, stream>>>(seedp, dec);
  k_spec<<<dim3(NCHUNK, NB), 16, 0, stream>>>(dec, Mend);
  k_fold<<<1, 256, 0, stream>>>(Mend, entry);
  k_apply<<<NB, 64, 0, stream>>>(dec, entry, st2);
  k_gather<<<dim3((OUTT + 255) / 256, NI, NB), 256, 0, stream>>>(x, st2, out);
}

// Round 3
// 273.272 us; speedup vs baseline: 1.1895x; 1.1895x over previous
//
#include <hip/hip_runtime.h>
#include <math.h>
#include <stdint.h>

// Problem constants (B=16, I=256, T=8192), x float32, out float32
#define T_LEN 8192
#define NSTEP 8189   // T-3 sampled steps
#define NB 16
#define NI 256
#define OUTT 8190    // T-2 output time length
#define CHUNK 128
#define NCHUNK 64    // 64*128 = 8192 >= NSTEP

// ---------------- threefry2x32 (JAX-compatible, 20 rounds) ----------------
__device__ __forceinline__ uint32_t rotl32(uint32_t v, int r) {
  return (v << r) | (v >> (32 - r));
}

__device__ __forceinline__ void tf2x32(uint32_t k0, uint32_t k1,
                                       uint32_t x0, uint32_t x1,
                                       uint32_t& o0, uint32_t& o1) {
  uint32_t k2 = k0 ^ k1 ^ 0x1BD11BDAu;
  x0 += k0; x1 += k1;
  // group 1 (rot set A: 13,15,26,6)
  x0 += x1; x1 = rotl32(x1, 13); x1 ^= x0;
  x0 += x1; x1 = rotl32(x1, 15); x1 ^= x0;
  x0 += x1; x1 = rotl32(x1, 26); x1 ^= x0;
  x0 += x1; x1 = rotl32(x1,  6); x1 ^= x0;
  x0 += k1; x1 += k2 + 1u;
  // group 2 (rot set B: 17,29,16,24)
  x0 += x1; x1 = rotl32(x1, 17); x1 ^= x0;
  x0 += x1; x1 = rotl32(x1, 29); x1 ^= x0;
  x0 += x1; x1 = rotl32(x1, 16); x1 ^= x0;
  x0 += x1; x1 = rotl32(x1, 24); x1 ^= x0;
  x0 += k2; x1 += k0 + 2u;
  // group 3 (A)
  x0 += x1; x1 = rotl32(x1, 13); x1 ^= x0;
  x0 += x1; x1 = rotl32(x1, 15); x1 ^= x0;
  x0 += x1; x1 = rotl32(x1, 26); x1 ^= x0;
  x0 += x1; x1 = rotl32(x1,  6); x1 ^= x0;
  x0 += k0; x1 += k1 + 3u;
  // group 4 (B)
  x0 += x1; x1 = rotl32(x1, 17); x1 ^= x0;
  x0 += x1; x1 = rotl32(x1, 29); x1 ^= x0;
  x0 += x1; x1 = rotl32(x1, 16); x1 ^= x0;
  x0 += x1; x1 = rotl32(x1, 24); x1 ^= x0;
  x0 += k1; x1 += k2 + 4u;
  // group 5 (A)
  x0 += x1; x1 = rotl32(x1, 13); x1 ^= x0;
  x0 += x1; x1 = rotl32(x1, 15); x1 ^= x0;
  x0 += x1; x1 = rotl32(x1, 26); x1 ^= x0;
  x0 += x1; x1 = rotl32(x1,  6); x1 ^= x0;
  x0 += k2; x1 += k0 + 5u;
  o0 = x0; o1 = x1;
}

// Correctly-rounded float32 log via double precision (validated bit-exact vs ref)
__device__ __forceinline__ float f32log_cr(float x) {
  return (float)log((double)x);
}

// jax uniform(minval=tiny,maxval=1) -> gumbel, exact f32 semantics (validated)
__device__ __forceinline__ float bits_to_gumbel(uint32_t bits) {
  uint32_t fb = (bits >> 9) | 0x3F800000u;
  float u = __uint_as_float(fb) - 1.0f;           // exact, in [0, 1)
  if (u == 0.0f) u = 1.17549435e-38f;             // finfo(f32).tiny
  float inner = f32log_cr(u);                     // < 0
  float outer = f32log_cr(-inner);
  return -outer;
}

__device__ __forceinline__ int chain_step(int sigma, uint32_t dv) {
  int s = (sigma == 5) ? (int)(dv >> 2) : (int)(dv & 3u);
  return (sigma % 3) * 3 + s;
}

// -------- Kernel 1 (fused): decision bytes + per-chunk 9-state maps --------
// Block = (chunk c, batch b), 128 threads; thread tid -> t = c*128+tid.
// Decision math byte-identical to the validated round-2 kernel.
__global__ void k_dec_spec(const int* __restrict__ seedp,
                           uint8_t* __restrict__ dec,
                           uint8_t* __restrict__ Mend) {
  __shared__ uint8_t ld[CHUNK];
  int c = blockIdx.x, b = blockIdx.y;
  int t = c * CHUNK + threadIdx.x;

  if (t < NSTEP) {
    uint32_t sk0 = 0u;                      // threefry_seed(int32): hi word 0
    uint32_t sk1 = (uint32_t)seedp[0];
    uint32_t kt0, kt1;
    tf2x32(sk0, sk1, 0u, (uint32_t)t, kt0, kt1);  // split key for step t

    float g[3];
#pragma unroll
    for (int e = 0; e < 3; ++e) {
      uint32_t o0, o1;
      tf2x32(kt0, kt1, 0u, (uint32_t)(3 * b + e), o0, o1);
      g[e] = bits_to_gumbel(o0 ^ o1);
    }

    const double pd = 0.1;
    const double sd = 1.0 - 2.0 * 0.1;
    const float Lp  = f32log_cr((float)pd);
    const float Ls  = f32log_cr((float)sd);
    const float Lb1 = f32log_cr((float)(sd / (pd + sd)));
    const float Lb2 = f32log_cr((float)(pd / (pd + sd)));

    float z0 = g[0] + Lp, z1 = g[1] + Ls, z2 = g[2] + Lp;
    int an = 0; float best = z0;
    if (z1 > best) { best = z1; an = 1; }
    if (z2 > best) { an = 2; }
    int as_ = ((g[2] + Lb2) > (g[1] + Lb1)) ? 2 : 1;

    uint8_t v = (uint8_t)(an | (as_ << 2));
    ld[threadIdx.x] = v;
    dec[b * T_LEN + t] = v;
  }
  __syncthreads();

  if (threadIdx.x < 9) {
    int sigma = threadIdx.x;
    int n = min(CHUNK, NSTEP - c * CHUNK);
    for (int k = 0; k < n; ++k) sigma = chain_step(sigma, ld[k]);
    Mend[(b * NCHUNK + c) * 9 + threadIdx.x] = (uint8_t)sigma;
  }
}

// -------- Kernel 2 (fused): fold chunk maps + apply -> st2 -----------------
// One block per batch, 64 threads (one per chunk).
__global__ void k_chain(const uint8_t* __restrict__ dec,
                        const uint8_t* __restrict__ Mend,
                        uint8_t* __restrict__ st2) {
  __shared__ uint8_t m[NCHUNK * 9];
  __shared__ uint8_t entry[NCHUNK];
  int b = blockIdx.x;
  for (int idx = threadIdx.x; idx < NCHUNK * 9; idx += blockDim.x)
    m[idx] = Mend[b * NCHUNK * 9 + idx];
  __syncthreads();
  if (threadIdx.x == 0) {
    int sigma = 4;  // (prev2,prev1) = (1,1)
    for (int cc = 0; cc < NCHUNK; ++cc) {
      entry[cc] = (uint8_t)sigma;
      sigma = m[cc * 9 + sigma];
    }
  }
  __syncthreads();
  int c = threadIdx.x;
  int sigma = entry[c];
  const uint8_t* d = dec + b * T_LEN;
  uint8_t* s2 = st2 + b * T_LEN;
  if (c == 0) s2[0] = 1;  // st[1] = 1 -> st2[0]
  int t0 = c * CHUNK, t1 = min(t0 + CHUNK, NSTEP);
  for (int t = t0; t < t1; ++t) {
    uint32_t dv = d[t];
    int s = (sigma == 5) ? (int)(dv >> 2) : (int)(dv & 3u);
    s2[t + 1] = (uint8_t)s;   // st[t+2] -> st2[t+1]
    sigma = (sigma % 3) * 3 + s;
  }
}

// -------- Kernel 3: vectorized gather --------------------------------------
// Thread handles 4 consecutive j: uchar4 st2 read, 4 scalar x loads (L1-hit
// overlap), two float2 stores (always 8B-aligned: row*8190 + j0 is even).
// float4 impossible: out row stride 8190*4B alternates 16B alignment by row.
__global__ void k_gather(const float* __restrict__ x,
                         const uint8_t* __restrict__ st2,
                         float* __restrict__ out) {
  int jt = blockIdx.x * blockDim.x + threadIdx.x;  // 0..2047
  int i = blockIdx.y, b = blockIdx.z;
  int j0 = jt * 4;
  if (j0 >= OUTT) return;
  const uint8_t* sp = st2 + b * T_LEN;
  size_t row = (size_t)(b * NI + i);
  const float* xr = x + row * (size_t)T_LEN;
  float* orow = out + row * (size_t)OUTT;
  uchar4 s4 = *(const uchar4*)(sp + j0);           // j0 % 4 == 0: aligned
  if (j0 + 4 <= OUTT) {
    float y0 = xr[j0 + 0 + s4.x];
    float y1 = xr[j0 + 1 + s4.y];
    float y2 = xr[j0 + 2 + s4.z];
    float y3 = xr[j0 + 3 + s4.w];
    *(float2*)(orow + j0)     = make_float2(y0, y1);
    *(float2*)(orow + j0 + 2) = make_float2(y2, y3);
  } else {
    // tail tile: exactly 2 outputs (8190 = 4*2047 + 2)
    float y0 = xr[j0 + 0 + s4.x];
    float y1 = xr[j0 + 1 + s4.y];
    *(float2*)(orow + j0) = make_float2(y0, y1);
  }
}

extern "C" void kernel_launch(void* const* d_in, const int* in_sizes, int n_in,
                              void* d_out, int out_size, void* d_ws, size_t ws_size,
                              hipStream_t stream) {
  const float* x   = (const float*)d_in[0];   // float32 input
  const int* seedp = (const int*)d_in[1];
  float* out       = (float*)d_out;           // float32 output

  uint8_t* ws    = (uint8_t*)d_ws;
  uint8_t* dec   = ws;                        // 16*8192 = 131072 B
  uint8_t* st2   = dec + NB * T_LEN;          // 131072 B
  uint8_t* Mend  = st2 + NB * T_LEN;          // 16*64*9 = 9216 B

  k_dec_spec<<<dim3(NCHUNK, NB), CHUNK, 0, stream>>>(seedp, dec, Mend);
  k_chain<<<NB, NCHUNK, 0, stream>>>(dec, Mend, st2);
  k_gather<<<dim3(8, NI, NB), 256, 0, stream>>>(x, st2, out);
}

// Round 4
// 264.460 us; speedup vs baseline: 1.2291x; 1.0333x over previous
//
#include <hip/hip_runtime.h>
#include <math.h>
#include <stdint.h>

// Problem constants (B=16, I=256, T=8192), x float32, out float32
#define T_LEN 8192
#define NSTEP 8189   // T-3 sampled steps
#define NB 16
#define NI 256
#define OUTT 8190    // T-2 output time length
#define CHUNK 128
#define NCHUNK 64    // 64*128 = 8192 >= NSTEP

// ---------------- threefry2x32 (JAX-compatible, 20 rounds) ----------------
__device__ __forceinline__ uint32_t rotl32(uint32_t v, int r) {
  return (v << r) | (v >> (32 - r));
}

__device__ __forceinline__ void tf2x32(uint32_t k0, uint32_t k1,
                                       uint32_t x0, uint32_t x1,
                                       uint32_t& o0, uint32_t& o1) {
  uint32_t k2 = k0 ^ k1 ^ 0x1BD11BDAu;
  x0 += k0; x1 += k1;
  // group 1 (rot set A: 13,15,26,6)
  x0 += x1; x1 = rotl32(x1, 13); x1 ^= x0;
  x0 += x1; x1 = rotl32(x1, 15); x1 ^= x0;
  x0 += x1; x1 = rotl32(x1, 26); x1 ^= x0;
  x0 += x1; x1 = rotl32(x1,  6); x1 ^= x0;
  x0 += k1; x1 += k2 + 1u;
  // group 2 (rot set B: 17,29,16,24)
  x0 += x1; x1 = rotl32(x1, 17); x1 ^= x0;
  x0 += x1; x1 = rotl32(x1, 29); x1 ^= x0;
  x0 += x1; x1 = rotl32(x1, 16); x1 ^= x0;
  x0 += x1; x1 = rotl32(x1, 24); x1 ^= x0;
  x0 += k2; x1 += k0 + 2u;
  // group 3 (A)
  x0 += x1; x1 = rotl32(x1, 13); x1 ^= x0;
  x0 += x1; x1 = rotl32(x1, 15); x1 ^= x0;
  x0 += x1; x1 = rotl32(x1, 26); x1 ^= x0;
  x0 += x1; x1 = rotl32(x1,  6); x1 ^= x0;
  x0 += k0; x1 += k1 + 3u;
  // group 4 (B)
  x0 += x1; x1 = rotl32(x1, 17); x1 ^= x0;
  x0 += x1; x1 = rotl32(x1, 29); x1 ^= x0;
  x0 += x1; x1 = rotl32(x1, 16); x1 ^= x0;
  x0 += x1; x1 = rotl32(x1, 24); x1 ^= x0;
  x0 += k1; x1 += k2 + 4u;
  // group 5 (A)
  x0 += x1; x1 = rotl32(x1, 13); x1 ^= x0;
  x0 += x1; x1 = rotl32(x1, 15); x1 ^= x0;
  x0 += x1; x1 = rotl32(x1, 26); x1 ^= x0;
  x0 += x1; x1 = rotl32(x1,  6); x1 ^= x0;
  x0 += k2; x1 += k0 + 5u;
  o0 = x0; o1 = x1;
}

// Correctly-rounded float32 log via double precision (validated bit-exact vs ref)
__device__ __forceinline__ float f32log_cr(float x) {
  return (float)log((double)x);
}

// jax uniform(minval=tiny,maxval=1) -> gumbel, exact f32 semantics (validated)
__device__ __forceinline__ float bits_to_gumbel(uint32_t bits) {
  uint32_t fb = (bits >> 9) | 0x3F800000u;
  float u = __uint_as_float(fb) - 1.0f;           // exact, in [0, 1)
  if (u == 0.0f) u = 1.17549435e-38f;             // finfo(f32).tiny
  float inner = f32log_cr(u);                     // < 0
  float outer = f32log_cr(-inner);
  return -outer;
}

__device__ __forceinline__ int chain_step(int sigma, uint32_t dv) {
  int s = (sigma == 5) ? (int)(dv >> 2) : (int)(dv & 3u);
  return (sigma % 3) * 3 + s;
}

// -------- Kernel 1 (fused): decision bytes + per-chunk 9-state maps --------
// Decision math byte-identical to the validated round-2/3 kernel.
__global__ void k_dec_spec(const int* __restrict__ seedp,
                           uint8_t* __restrict__ dec,
                           uint8_t* __restrict__ Mend) {
  __shared__ uint8_t ld[CHUNK];
  int c = blockIdx.x, b = blockIdx.y;
  int t = c * CHUNK + threadIdx.x;

  if (t < NSTEP) {
    uint32_t sk0 = 0u;                      // threefry_seed(int32): hi word 0
    uint32_t sk1 = (uint32_t)seedp[0];
    uint32_t kt0, kt1;
    tf2x32(sk0, sk1, 0u, (uint32_t)t, kt0, kt1);  // split key for step t

    float g[3];
#pragma unroll
    for (int e = 0; e < 3; ++e) {
      uint32_t o0, o1;
      tf2x32(kt0, kt1, 0u, (uint32_t)(3 * b + e), o0, o1);
      g[e] = bits_to_gumbel(o0 ^ o1);
    }

    const double pd = 0.1;
    const double sd = 1.0 - 2.0 * 0.1;
    const float Lp  = f32log_cr((float)pd);
    const float Ls  = f32log_cr((float)sd);
    const float Lb1 = f32log_cr((float)(sd / (pd + sd)));
    const float Lb2 = f32log_cr((float)(pd / (pd + sd)));

    float z0 = g[0] + Lp, z1 = g[1] + Ls, z2 = g[2] + Lp;
    int an = 0; float best = z0;
    if (z1 > best) { best = z1; an = 1; }
    if (z2 > best) { an = 2; }
    int as_ = ((g[2] + Lb2) > (g[1] + Lb1)) ? 2 : 1;

    uint8_t v = (uint8_t)(an | (as_ << 2));
    ld[threadIdx.x] = v;
    dec[b * T_LEN + t] = v;
  }
  __syncthreads();

  if (threadIdx.x < 9) {
    int sigma = threadIdx.x;
    int n = min(CHUNK, NSTEP - c * CHUNK);
    for (int k = 0; k < n; ++k) sigma = chain_step(sigma, ld[k]);
    Mend[(b * NCHUNK + c) * 9 + threadIdx.x] = (uint8_t)sigma;
  }
}

// -------- Kernel 2 (fused): fold chunk maps + apply -> st2 -----------------
// One block per batch, 64 threads (one per chunk). Apply loop reads dec as
// uint32 words (unrolled -> loads hoisted, no per-byte load latency chain).
__global__ void k_chain(const uint8_t* __restrict__ dec,
                        const uint8_t* __restrict__ Mend,
                        uint8_t* __restrict__ st2) {
  __shared__ uint8_t m[NCHUNK * 9];
  __shared__ uint8_t entry[NCHUNK];
  int b = blockIdx.x;
  for (int idx = threadIdx.x; idx < NCHUNK * 9; idx += blockDim.x)
    m[idx] = Mend[b * NCHUNK * 9 + idx];
  __syncthreads();
  if (threadIdx.x == 0) {
    int sigma = 4;  // (prev2,prev1) = (1,1)
    for (int cc = 0; cc < NCHUNK; ++cc) {
      entry[cc] = (uint8_t)sigma;
      sigma = m[cc * 9 + sigma];
    }
  }
  __syncthreads();
  int c = threadIdx.x;
  int t0 = c * CHUNK;
  int sigma = entry[c];
  const uint32_t* dw = (const uint32_t*)(dec + b * T_LEN + t0);  // 4-aligned
  uint8_t* s2 = st2 + b * T_LEN;
  if (c == 0) s2[0] = 1;  // st[1] = 1 -> st2[0]
#pragma unroll 8
  for (int wi = 0; wi < CHUNK / 4; ++wi) {
    uint32_t word = dw[wi];
#pragma unroll
    for (int r = 0; r < 4; ++r) {
      int t = t0 + 4 * wi + r;
      uint32_t dv = (word >> (8 * r)) & 0xFFu;
      int s = (sigma == 5) ? (int)(dv >> 2) : (int)(dv & 3u);
      if (t < NSTEP) s2[t + 1] = (uint8_t)s;  // guard: don't stomp next batch's st2[0]
      sigma = (sigma % 3) * 3 + s;
    }
  }
}

// -------- Kernel 3: register-window gather ---------------------------------
// Thread handles 16 consecutive j. Loads window x[j0..j0+17] via 4 float4 +
// 1 float2 (independent of st2 -> full load pipelining), st2 via uint4,
// selects with static-index cndmask chains, stores 8 float2 (8B-aligned
// always; float4 impossible: out row stride 8190 alternates 16B parity).
__global__ void k_gather(const float* __restrict__ x,
                         const uint8_t* __restrict__ st2,
                         float* __restrict__ out) {
  int jt = blockIdx.x * blockDim.x + threadIdx.x;  // 0..511
  int i = blockIdx.y, b = blockIdx.z;
  int j0 = jt * 16;
  size_t row = (size_t)(b * NI + i);
  const float* xr = x + row * (size_t)T_LEN;
  float* orow = out + row * (size_t)OUTT;

  uint4 q = *(const uint4*)(st2 + b * T_LEN + j0);  // j0%16==0: aligned
  uint32_t wbits[4] = {q.x, q.y, q.z, q.w};

  float w[18];
  float4 a0 = *(const float4*)(xr + j0);
  float4 a1 = *(const float4*)(xr + j0 + 4);
  float4 a2 = *(const float4*)(xr + j0 + 8);
  float4 a3 = *(const float4*)(xr + j0 + 12);
  w[0]=a0.x; w[1]=a0.y; w[2]=a0.z; w[3]=a0.w;
  w[4]=a1.x; w[5]=a1.y; w[6]=a1.z; w[7]=a1.w;
  w[8]=a2.x; w[9]=a2.y; w[10]=a2.z; w[11]=a2.w;
  w[12]=a3.x; w[13]=a3.y; w[14]=a3.z; w[15]=a3.w;

  if (j0 + 16 <= OUTT) {                    // full tile (all but last thread)
    float2 e = *(const float2*)(xr + j0 + 16);
    w[16] = e.x; w[17] = e.y;
    float res[16];
#pragma unroll
    for (int m = 0; m < 4; ++m) {
      uint32_t ww = wbits[m];
#pragma unroll
      for (int r = 0; r < 4; ++r) {
        int k = 4 * m + r;
        int s = (int)((ww >> (8 * r)) & 0xFFu);
        res[k] = (s == 0) ? w[k] : ((s == 1) ? w[k + 1] : w[k + 2]);
      }
    }
#pragma unroll
    for (int m = 0; m < 8; ++m)
      *(float2*)(orow + j0 + 2 * m) = make_float2(res[2 * m], res[2 * m + 1]);
  } else {                                   // tail tile: 14 outputs (j0=8176)
    float res[14];
#pragma unroll
    for (int m = 0; m < 4; ++m) {
      uint32_t ww = wbits[m];
#pragma unroll
      for (int r = 0; r < 4; ++r) {
        int k = 4 * m + r;
        if (k >= 14) break;
        int s = (int)((ww >> (8 * r)) & 0xFFu);   // w[k+2] max = w[15]: in range
        res[k] = (s == 0) ? w[k] : ((s == 1) ? w[k + 1] : w[k + 2]);
      }
    }
#pragma unroll
    for (int m = 0; m < 7; ++m)
      *(float2*)(orow + j0 + 2 * m) = make_float2(res[2 * m], res[2 * m + 1]);
  }
}

extern "C" void kernel_launch(void* const* d_in, const int* in_sizes, int n_in,
                              void* d_out, int out_size, void* d_ws, size_t ws_size,
                              hipStream_t stream) {
  const float* x   = (const float*)d_in[0];   // float32 input
  const int* seedp = (const int*)d_in[1];
  float* out       = (float*)d_out;           // float32 output

  uint8_t* ws    = (uint8_t*)d_ws;
  uint8_t* dec   = ws;                        // 16*8192 = 131072 B
  uint8_t* st2   = dec + NB * T_LEN;          // 131072 B
  uint8_t* Mend  = st2 + NB * T_LEN;          // 16*64*9 = 9216 B

  k_dec_spec<<<dim3(NCHUNK, NB), CHUNK, 0, stream>>>(seedp, dec, Mend);
  k_chain<<<NB, NCHUNK, 0, stream>>>(dec, Mend, st2);
  // 512 j-tiles of 16 per row -> grid.x = 2 blocks of 256 threads
  k_gather<<<dim3(2, NI, NB), 256, 0, stream>>>(x, st2, out);
}